// Round 5
// baseline (624.082 us; speedup 1.0000x reference)
//
#include <hip/hip_runtime.h>
#include <hip/hip_bf16.h>

#define EMB 64
#define BKT_BITS 10                      // 1024 items per bucket
#define BKT_SZ   (1 << BKT_BITS)
#define U_BITS   18                      // NU=200000 < 2^18
#define U_MASK   ((1u << U_BITS) - 1u)

__device__ __forceinline__ float bf2f(unsigned short h) {
    return __uint_as_float(((unsigned)h) << 16);
}
__device__ __forceinline__ unsigned short f2bf(float f) {
    unsigned u = __float_as_uint(f);
    unsigned r = (u + 0x7fffu + ((u >> 16) & 1u)) >> 16;  // RNE
    return (unsigned short)r;
}

// ---- K1: user row_ptr (binary search) + item degree histogram, merged ----
__global__ void k1_kernel(const int* __restrict__ row, const int* __restrict__ colh,
                          int* __restrict__ urp, int* __restrict__ degit,
                          int NU, int Eh, int urp_blocks) {
    if ((int)blockIdx.x < urp_blocks) {
        int r = blockIdx.x * blockDim.x + threadIdx.x;
        if (r > NU) return;
        if (r == NU) { urp[NU] = Eh; return; }
        int lo = 0, hi = Eh;
        while (lo < hi) {
            int mid = (lo + hi) >> 1;
            if (row[mid] < r) lo = mid + 1; else hi = mid;
        }
        urp[r] = lo;
    } else {
        int e = (blockIdx.x - urp_blocks) * blockDim.x + threadIdx.x;
        if (e < Eh) atomicAdd(&degit[colh[e] - NU], 1);
    }
}

// ---- K3: scan1 + dinv + y0-init fused (all sections independent) ----
// y0 = bf16(d^-1/2 * x0): pre-scaled rows kill the per-edge dinv gather in spmm.
__global__ void k3_kernel(const int* __restrict__ degit, int* __restrict__ excl,
                          int* __restrict__ partials,
                          const int* __restrict__ urp, float* __restrict__ dinv,
                          const float* __restrict__ ue, const float* __restrict__ ie,
                          unsigned short* __restrict__ y0,
                          int NU, int NI, int N, long nu_elems, long total,
                          int nb_s1, int nb_dv) {
    int b = blockIdx.x;
    if (b < nb_s1) {
        __shared__ int sh[256];
        int t = threadIdx.x;
        int base = b * 1024 + t * 4;
        int d0 = (base + 0 < NI) ? degit[base + 0] : 0;
        int d1 = (base + 1 < NI) ? degit[base + 1] : 0;
        int d2 = (base + 2 < NI) ? degit[base + 2] : 0;
        int d3 = (base + 3 < NI) ? degit[base + 3] : 0;
        int tsum = d0 + d1 + d2 + d3;
        sh[t] = tsum;
        __syncthreads();
        for (int off = 1; off < 256; off <<= 1) {
            int v = (t >= off) ? sh[t - off] : 0;
            __syncthreads();
            sh[t] += v;
            __syncthreads();
        }
        int excl_t = sh[t] - tsum;
        if (base + 0 < NI) excl[base + 0] = excl_t;
        if (base + 1 < NI) excl[base + 1] = excl_t + d0;
        if (base + 2 < NI) excl[base + 2] = excl_t + d0 + d1;
        if (base + 3 < NI) excl[base + 3] = excl_t + d0 + d1 + d2;
        if (t == 255) partials[b] = sh[t];
    } else if (b < nb_s1 + nb_dv) {
        int i = (b - nb_s1) * blockDim.x + threadIdx.x;
        if (i >= N) return;
        int d = (i < NU) ? (urp[i + 1] - urp[i]) : degit[i - NU];
        dinv[i] = rsqrtf((float)d + 1.0f);
    } else {
        long j4 = ((long)(b - nb_s1 - nb_dv) * blockDim.x + threadIdx.x) * 4;
        if (j4 >= total) return;
        int node = (int)(j4 >> 6);
        int d = (node < NU) ? (urp[node + 1] - urp[node]) : degit[node - NU];
        float sc = rsqrtf((float)d + 1.0f);
        float4 v = (j4 < nu_elems) ? ((const float4*)ue)[j4 >> 2]
                                   : ((const float4*)ie)[(j4 - nu_elems) >> 2];
        ushort4 o;
        o.x = f2bf(sc * v.x); o.y = f2bf(sc * v.y);
        o.z = f2bf(sc * v.z); o.w = f2bf(sc * v.w);
        ((ushort4*)y0)[j4 >> 2] = o;
    }
}

__global__ void scan2_kernel(int* __restrict__ partials, int nb) {
    __shared__ int sh[512];
    int t = threadIdx.x;
    int v = (t < nb) ? partials[t] : 0;
    sh[t] = v;
    __syncthreads();
    for (int off = 1; off < 512; off <<= 1) {
        int u = (t >= off) ? sh[t - off] : 0;
        __syncthreads();
        sh[t] += u;
        __syncthreads();
    }
    if (t < nb) partials[t] = sh[t] - v;  // exclusive
}

// ---- scan3: finalize irp/cursor + seed bucket cursors ----
__global__ void scan3_kernel(const int* __restrict__ excl, const int* __restrict__ partials,
                             int* __restrict__ irp, int* __restrict__ cursor,
                             int* __restrict__ bcur, int NI, int Eh) {
    int i = blockIdx.x * blockDim.x + threadIdx.x;
    if (i < NI) {
        int v = excl[i] + partials[i >> 10];
        irp[i] = v;
        cursor[i] = v;
        if ((i & (BKT_SZ - 1)) == 0) bcur[i >> BKT_BITS] = v;
    }
    if (i == NI) irp[NI] = Eh;
}

// ---- Pass A: radix-partition edges into item-range buckets ----
// Each block: LDS histogram of its 1024 edges over NB buckets, one contiguous
// run reservation per bucket (single atomicAdd on bcur), packed writes
// (item_off<<18 | user) in ~40B runs. Kills the 4B-random-scatter pattern.
__global__ void passA_kernel(const int* __restrict__ rowh, const int* __restrict__ colh,
                             int* __restrict__ bcur, unsigned* __restrict__ staging,
                             int Eh, int NU, int NB) {
    __shared__ int cnt[512];
    __shared__ int base[512];
    int t = threadIdx.x;
    for (int j = t; j < NB; j += 256) cnt[j] = 0;
    __syncthreads();
    long cb = (long)blockIdx.x * 1024;
    int b[4], rk[4];
    unsigned pk[4];
#pragma unroll
    for (int j = 0; j < 4; ++j) {
        long e = cb + j * 256 + t;
        if (e < Eh) {
            int u = rowh[e];
            int loc = colh[e] - NU;
            b[j] = loc >> BKT_BITS;
            pk[j] = ((unsigned)(loc & (BKT_SZ - 1)) << U_BITS) | (unsigned)u;
            rk[j] = atomicAdd(&cnt[b[j]], 1);
        } else {
            b[j] = -1;
        }
    }
    __syncthreads();
    for (int j = t; j < NB; j += 256)
        base[j] = cnt[j] ? atomicAdd(&bcur[j], cnt[j]) : 0;
    __syncthreads();
#pragma unroll
    for (int j = 0; j < 4; ++j)
        if (b[j] >= 0) staging[base[b[j]] + rk[j]] = pk[j];
}

// ---- per-node SpMM body over pre-scaled y rows: pure gather+add ----
__device__ __forceinline__ void spmm_node(
    int i, int q,
    const int* __restrict__ urp, const int* __restrict__ irp,
    const int* __restrict__ colg, const int* __restrict__ icols,
    const float* __restrict__ dinv,
    const unsigned short* __restrict__ yc,
    unsigned short* __restrict__ yn,
    const unsigned short* __restrict__ y0b,
    const unsigned short* __restrict__ y1b,
    float* __restrict__ out, int NU) {
    const int* list;
    int s, e;
    if (i < NU) { s = urp[i]; e = urp[i + 1]; list = colg; }
    else        { int j = i - NU; s = irp[j]; e = irp[j + 1]; list = icols; }
    float di = dinv[i];
    const ushort4* __restrict__ yc4 = (const ushort4*)yc;

    long p = (long)i * 16 + q;
    ushort4 sv = yc4[p];  // self row, hoisted

    float ax = 0.f, ay = 0.f, az = 0.f, aw = 0.f;
    for (int k0 = s; k0 < e; k0 += 8) {
        int   c[8];
        float w[8];
#pragma unroll
        for (int j = 0; j < 8; ++j) {
            int k = k0 + j;
            bool v = (k < e);
            c[j] = v ? list[k] : 0;
            w[j] = v ? 1.0f : 0.0f;
        }
        ushort4 u[8];
#pragma unroll
        for (int j = 0; j < 8; ++j) u[j] = yc4[(long)c[j] * 16 + q];  // 8 gathers in flight
#pragma unroll
        for (int j = 0; j < 8; ++j) {
            ax += w[j] * bf2f(u[j].x);
            ay += w[j] * bf2f(u[j].y);
            az += w[j] * bf2f(u[j].z);
            aw += w[j] * bf2f(u[j].w);
        }
    }

    ax += bf2f(sv.x);
    ay += bf2f(sv.y);
    az += bf2f(sv.z);
    aw += bf2f(sv.w);

    if (yn) {
        float t = di * di;
        ushort4 o;
        o.x = f2bf(t * ax); o.y = f2bf(t * ay); o.z = f2bf(t * az); o.w = f2bf(t * aw);
        ((ushort4*)yn)[p] = o;
    } else {
        ushort4 a0 = ((const ushort4*)y0b)[p];
        ushort4 a1 = ((const ushort4*)y1b)[p];
        float inv = 1.0f / di;  // sqrt(deg+1)
        float4 o;
        o.x = (bf2f(a0.x) + bf2f(a1.x) + bf2f(sv.x)) * inv + di * ax;
        o.y = (bf2f(a0.y) + bf2f(a1.y) + bf2f(sv.y)) * inv + di * ay;
        o.z = (bf2f(a0.z) + bf2f(a1.z) + bf2f(sv.z)) * inv + di * az;
        o.w = (bf2f(a0.w) + bf2f(a1.w) + bf2f(sv.w)) * inv + di * aw;
        ((float4*)out)[p] = o;
    }
}

// ---- spmm over node range [base, base+cnt) ----
__global__ void spmm_kernel(int base, int cnt,
                            const int* __restrict__ urp, const int* __restrict__ irp,
                            const int* __restrict__ colg, const int* __restrict__ icols,
                            const float* __restrict__ dinv,
                            const unsigned short* __restrict__ yc,
                            unsigned short* __restrict__ yn,
                            const unsigned short* __restrict__ y0b,
                            const unsigned short* __restrict__ y1b,
                            float* __restrict__ out, int NU) {
    long t = (long)blockIdx.x * blockDim.x + threadIdx.x;
    int r = (int)(t >> 4);
    if (r >= cnt) return;
    spmm_node(base + r, (int)(t & 15), urp, irp, colg, icols, dinv,
              yc, yn, y0b, y1b, out, NU);
}

// ---- M6: Pass B (bucket-local icols scatter, ONE BLOCK PER BUCKET = one
// ---- XCD per ~40KB window -> writeback == |icols|) || L0-user spmm.
__global__ void m6_kernel(const unsigned* __restrict__ staging,
                          const int* __restrict__ irp, int* __restrict__ cursor,
                          int* __restrict__ icols, int NB, int NI,
                          const int* __restrict__ urp,
                          const int* __restrict__ colg,
                          const float* __restrict__ dinv,
                          const unsigned short* __restrict__ yc,
                          unsigned short* __restrict__ yn, int NU) {
    int b = (int)blockIdx.x;
    if (b < NB) {
        int lo = b << BKT_BITS;
        int hi = lo + BKT_SZ; if (hi > NI) hi = NI;
        int start = irp[lo], end = irp[hi];
        for (int k = start + (int)threadIdx.x; k < end; k += 256) {
            unsigned v = staging[k];
            int u   = (int)(v & U_MASK);
            int loc = lo + (int)(v >> U_BITS);
            int pos = atomicAdd(&cursor[loc], 1);
            icols[pos] = u;
        }
    } else {
        long t = (long)(b - NB) * blockDim.x + threadIdx.x;
        int i = (int)(t >> 4);
        if (i >= NU) return;  // users only: never touches icols
        spmm_node(i, (int)(t & 15), urp, irp, colg, /*icols=*/nullptr, dinv,
                  yc, yn, nullptr, nullptr, nullptr, NU);
    }
}

extern "C" void kernel_launch(void* const* d_in, const int* in_sizes, int n_in,
                              void* d_out, int out_size, void* d_ws, size_t ws_size,
                              hipStream_t stream) {
    const int*   edge_index = (const int*)d_in[0];   // [2, E]
    const float* user_emb   = (const float*)d_in[1]; // [NU, 64]
    const float* item_emb   = (const float*)d_in[2]; // [NI, 64]
    float* out = (float*)d_out;

    const int  E  = in_sizes[0] / 2;
    const int  Eh = E / 2;             // first half: user rows (sorted), cols = items
    const int  NU = in_sizes[1] / EMB;
    const int  NI = in_sizes[2] / EMB;
    const int  N  = NU + NI;
    const long total = (long)N * EMB;

    const int* row = edge_index;       // [E]
    const int* col = edge_index + E;   // [E]
    const int* rowh = row;             // first Eh: sorted user ids
    const int* colh = col;             // first Eh: item ids (random)

    // workspace layout:
    // urp[NU+1] | degit[NI] | excl[NI] | partials[512] | bcur[512] | irp[NI+1] |
    // cursor[NI] | icols[Eh] | dinv[N] f | y0/y1/y2 [total] bf16 (128B-aligned)
    int*   urp      = (int*)d_ws;
    int*   degit    = urp + (NU + 1);
    int*   excl     = degit + NI;
    int*   partials = excl + NI;
    int*   bcur     = partials + 512;
    int*   irp      = bcur + 512;
    int*   cursor   = irp + (NI + 1);
    int*   icols    = cursor + NI;
    float* dinv     = (float*)(icols + Eh);
    unsigned short* y0 = (unsigned short*)(((uintptr_t)(dinv + N) + 127) & ~(uintptr_t)127);
    unsigned short* y1 = y0 + total;   // total*2 bytes is a multiple of 128
    unsigned short* y2 = y1 + total;
    // pass-A staging (Eh * 4B = ~4MB) lives in y1's ITEM half (12.8MB), which is
    // dead until item-L0 (runs after pass B consumes the staging).
    unsigned* staging = (unsigned*)(y1 + (long)NU * EMB);

    hipMemsetAsync(degit, 0, (size_t)NI * sizeof(int), stream);

    // K1: urp + ideg
    int urp_blocks  = (NU + 256) / 256;
    int ideg_blocks = (Eh + 255) / 256;
    k1_kernel<<<urp_blocks + ideg_blocks, 256, 0, stream>>>(row, colh, urp, degit,
                                                            NU, Eh, urp_blocks);

    // K3: scan1 + dinv + y0-init
    int nb_s1 = (NI + 1023) / 1024;              // <= 512
    int nb_dv = (N + 255) / 256;
    int nb_in = (int)((total / 4 + 255) / 256);
    k3_kernel<<<nb_s1 + nb_dv + nb_in, 256, 0, stream>>>(degit, excl, partials,
                                                         urp, dinv, user_emb, item_emb, y0,
                                                         NU, NI, N, (long)NU * EMB, total,
                                                         nb_s1, nb_dv);

    scan2_kernel<<<1, 512, 0, stream>>>(partials, nb_s1);
    scan3_kernel<<<(NI + 1 + 255) / 256, 256, 0, stream>>>(excl, partials, irp, cursor,
                                                           bcur, NI, Eh);

    // Pass A: bucket edges (runs-coalesced staging writes)
    int NB = (NI + BKT_SZ - 1) >> BKT_BITS;      // <= 512 (LDS arrays sized 512)
    int nb_pa = (Eh + 1023) / 1024;
    passA_kernel<<<nb_pa, 256, 0, stream>>>(rowh, colh, bcur, staging, Eh, NU, NB);

    // M6: pass B (NB blocks, launched first) || L0-users (y1[users])
    int nb_us = (int)(((long)NU * 16 + 255) / 256);
    m6_kernel<<<NB + nb_us, 256, 0, stream>>>(staging, irp, cursor, icols, NB, NI,
                                              urp, col, dinv, y0, y1, NU);

    // L0 items: y1[items] (needs icols; overwrites the dead staging region)
    int nb_it = (int)(((long)NI * 16 + 255) / 256);
    spmm_kernel<<<nb_it, 256, 0, stream>>>(NU, NI, urp, irp, col, icols, dinv,
                                           y0, y1, nullptr, nullptr, nullptr, NU);

    // L1: y2 = layer(y1), all nodes
    int nb_all = (int)(((long)N * 16 + 255) / 256);
    spmm_kernel<<<nb_all, 256, 0, stream>>>(0, N, urp, irp, col, icols, dinv,
                                            y1, y2, nullptr, nullptr, nullptr, NU);

    // L2 (fused final): out = (y0+y1+y2)/d + d*s
    spmm_kernel<<<nb_all, 256, 0, stream>>>(0, N, urp, irp, col, icols, dinv,
                                            y2, nullptr, y0, y1, out, NU);
}

// Round 6
// 602.292 us; speedup vs baseline: 1.0362x; 1.0362x over previous
//
#include <hip/hip_runtime.h>
#include <hip/hip_bf16.h>

#define EMB 64
#define BKT_BITS 10                      // 1024 items per bucket
#define BKT_SZ   (1 << BKT_BITS)
#define U_BITS   18                      // NU=200000 < 2^18
#define U_MASK   ((1u << U_BITS) - 1u)

__device__ __forceinline__ float bf2f(unsigned short h) {
    return __uint_as_float(((unsigned)h) << 16);
}
__device__ __forceinline__ unsigned short f2bf(float f) {
    unsigned u = __float_as_uint(f);
    unsigned r = (u + 0x7fffu + ((u >> 16) & 1u)) >> 16;  // RNE
    return (unsigned short)r;
}

// ---- K1: user row_ptr (binary search) + item degree histogram, merged ----
__global__ void k1_kernel(const int* __restrict__ row, const int* __restrict__ colh,
                          int* __restrict__ urp, int* __restrict__ degit,
                          int NU, int Eh, int urp_blocks) {
    if ((int)blockIdx.x < urp_blocks) {
        int r = blockIdx.x * blockDim.x + threadIdx.x;
        if (r > NU) return;
        if (r == NU) { urp[NU] = Eh; return; }
        int lo = 0, hi = Eh;
        while (lo < hi) {
            int mid = (lo + hi) >> 1;
            if (row[mid] < r) lo = mid + 1; else hi = mid;
        }
        urp[r] = lo;
    } else {
        int e = (blockIdx.x - urp_blocks) * blockDim.x + threadIdx.x;
        if (e < Eh) atomicAdd(&degit[colh[e] - NU], 1);
    }
}

// ---- K3: scan1 + dinv + y0-init fused (all sections independent) ----
// y0 = bf16(d^-1/2 * x0): pre-scaled rows kill the per-edge dinv gather in spmm.
__global__ void k3_kernel(const int* __restrict__ degit, int* __restrict__ excl,
                          int* __restrict__ partials,
                          const int* __restrict__ urp, float* __restrict__ dinv,
                          const float* __restrict__ ue, const float* __restrict__ ie,
                          unsigned short* __restrict__ y0,
                          int NU, int NI, int N, long nu_elems, long total,
                          int nb_s1, int nb_dv) {
    int b = blockIdx.x;
    if (b < nb_s1) {
        __shared__ int sh[256];
        int t = threadIdx.x;
        int base = b * 1024 + t * 4;
        int d0 = (base + 0 < NI) ? degit[base + 0] : 0;
        int d1 = (base + 1 < NI) ? degit[base + 1] : 0;
        int d2 = (base + 2 < NI) ? degit[base + 2] : 0;
        int d3 = (base + 3 < NI) ? degit[base + 3] : 0;
        int tsum = d0 + d1 + d2 + d3;
        sh[t] = tsum;
        __syncthreads();
        for (int off = 1; off < 256; off <<= 1) {
            int v = (t >= off) ? sh[t - off] : 0;
            __syncthreads();
            sh[t] += v;
            __syncthreads();
        }
        int excl_t = sh[t] - tsum;
        if (base + 0 < NI) excl[base + 0] = excl_t;
        if (base + 1 < NI) excl[base + 1] = excl_t + d0;
        if (base + 2 < NI) excl[base + 2] = excl_t + d0 + d1;
        if (base + 3 < NI) excl[base + 3] = excl_t + d0 + d1 + d2;
        if (t == 255) partials[b] = sh[t];
    } else if (b < nb_s1 + nb_dv) {
        int i = (b - nb_s1) * blockDim.x + threadIdx.x;
        if (i >= N) return;
        int d = (i < NU) ? (urp[i + 1] - urp[i]) : degit[i - NU];
        dinv[i] = rsqrtf((float)d + 1.0f);
    } else {
        long j4 = ((long)(b - nb_s1 - nb_dv) * blockDim.x + threadIdx.x) * 4;
        if (j4 >= total) return;
        int node = (int)(j4 >> 6);
        int d = (node < NU) ? (urp[node + 1] - urp[node]) : degit[node - NU];
        float sc = rsqrtf((float)d + 1.0f);
        float4 v = (j4 < nu_elems) ? ((const float4*)ue)[j4 >> 2]
                                   : ((const float4*)ie)[(j4 - nu_elems) >> 2];
        ushort4 o;
        o.x = f2bf(sc * v.x); o.y = f2bf(sc * v.y);
        o.z = f2bf(sc * v.z); o.w = f2bf(sc * v.w);
        ((ushort4*)y0)[j4 >> 2] = o;
    }
}

__global__ void scan2_kernel(int* __restrict__ partials, int nb) {
    __shared__ int sh[512];
    int t = threadIdx.x;
    int v = (t < nb) ? partials[t] : 0;
    sh[t] = v;
    __syncthreads();
    for (int off = 1; off < 512; off <<= 1) {
        int u = (t >= off) ? sh[t - off] : 0;
        __syncthreads();
        sh[t] += u;
        __syncthreads();
    }
    if (t < nb) partials[t] = sh[t] - v;  // exclusive
}

// ---- scan3: finalize irp/cursor + seed bucket cursors ----
__global__ void scan3_kernel(const int* __restrict__ excl, const int* __restrict__ partials,
                             int* __restrict__ irp, int* __restrict__ cursor,
                             int* __restrict__ bcur, int NI, int Eh) {
    int i = blockIdx.x * blockDim.x + threadIdx.x;
    if (i < NI) {
        int v = excl[i] + partials[i >> 10];
        irp[i] = v;
        cursor[i] = v;
        if ((i & (BKT_SZ - 1)) == 0) bcur[i >> BKT_BITS] = v;
    }
    if (i == NI) irp[NI] = Eh;
}

// ---- Pass A: radix-partition edges into item-range buckets ----
__global__ void passA_kernel(const int* __restrict__ rowh, const int* __restrict__ colh,
                             int* __restrict__ bcur, unsigned* __restrict__ staging,
                             int Eh, int NU, int NB) {
    __shared__ int cnt[512];
    __shared__ int base[512];
    int t = threadIdx.x;
    for (int j = t; j < NB; j += 256) cnt[j] = 0;
    __syncthreads();
    long cb = (long)blockIdx.x * 1024;
    int b[4], rk[4];
    unsigned pk[4];
#pragma unroll
    for (int j = 0; j < 4; ++j) {
        long e = cb + j * 256 + t;
        if (e < Eh) {
            int u = rowh[e];
            int loc = colh[e] - NU;
            b[j] = loc >> BKT_BITS;
            pk[j] = ((unsigned)(loc & (BKT_SZ - 1)) << U_BITS) | (unsigned)u;
            rk[j] = atomicAdd(&cnt[b[j]], 1);
        } else {
            b[j] = -1;
        }
    }
    __syncthreads();
    for (int j = t; j < NB; j += 256)
        base[j] = cnt[j] ? atomicAdd(&bcur[j], cnt[j]) : 0;
    __syncthreads();
#pragma unroll
    for (int j = 0; j < 4; ++j)
        if (b[j] >= 0) staging[base[b[j]] + rk[j]] = pk[j];
}

// ---- single-gather spmm body (used for users-L0 inside m6) ----
__device__ __forceinline__ void spmm_node_l0u(
    int i, int q,
    const int* __restrict__ urp, const int* __restrict__ colg,
    const float* __restrict__ dinv,
    const unsigned short* __restrict__ yc,
    unsigned short* __restrict__ yn) {
    int s = urp[i], e = urp[i + 1];
    float di = dinv[i];
    const ushort4* __restrict__ yc4 = (const ushort4*)yc;
    long p = (long)i * 16 + q;
    ushort4 sv = yc4[p];

    float ax = 0.f, ay = 0.f, az = 0.f, aw = 0.f;
    for (int k0 = s; k0 < e; k0 += 8) {
        int   c[8];
        float w[8];
#pragma unroll
        for (int j = 0; j < 8; ++j) {
            int k = k0 + j;
            bool v = (k < e);
            c[j] = v ? colg[k] : 0;
            w[j] = v ? 1.0f : 0.0f;
        }
        ushort4 u[8];
#pragma unroll
        for (int j = 0; j < 8; ++j) u[j] = yc4[(long)c[j] * 16 + q];
#pragma unroll
        for (int j = 0; j < 8; ++j) {
            ax += w[j] * bf2f(u[j].x);
            ay += w[j] * bf2f(u[j].y);
            az += w[j] * bf2f(u[j].z);
            aw += w[j] * bf2f(u[j].w);
        }
    }
    ax += bf2f(sv.x); ay += bf2f(sv.y); az += bf2f(sv.z); aw += bf2f(sv.w);
    float t = di * di;
    ushort4 o;
    o.x = f2bf(t * ax); o.y = f2bf(t * ay); o.z = f2bf(t * az); o.w = f2bf(t * aw);
    ((ushort4*)yn)[p] = o;
}

// ---- M6: Pass B (bucket-local icols scatter, one block/bucket) || users-L0 ----
__global__ void m6_kernel(const unsigned* __restrict__ staging,
                          const int* __restrict__ irp, int* __restrict__ cursor,
                          int* __restrict__ icols, int NB, int NI,
                          const int* __restrict__ urp,
                          const int* __restrict__ colg,
                          const float* __restrict__ dinv,
                          const unsigned short* __restrict__ y0,
                          unsigned short* __restrict__ y1, int NU) {
    int b = (int)blockIdx.x;
    if (b < NB) {
        int lo = b << BKT_BITS;
        int hi = lo + BKT_SZ; if (hi > NI) hi = NI;
        int start = irp[lo], end = irp[hi];
        for (int k = start + (int)threadIdx.x; k < end; k += 256) {
            unsigned v = staging[k];
            int u   = (int)(v & U_MASK);
            int loc = lo + (int)(v >> U_BITS);
            int pos = atomicAdd(&cursor[loc], 1);
            icols[pos] = u;
        }
    } else {
        long t = (long)(b - NB) * blockDim.x + threadIdx.x;
        int i = (int)(t >> 4);
        if (i >= NU) return;
        spmm_node_l0u(i, (int)(t & 15), urp, colg, dinv, y0, y1);
    }
}

// ---- D2: items fused L0+L1 — one pass over user list, dual gather y0/y1 ----
// y1[i] = d^2 (sum_u y0[u] + y0[i]);  y2[i] = d^2 (sum_u y1[u] + bf16(y1[i]))
__global__ void d2_kernel(const int* __restrict__ irp, const int* __restrict__ icols,
                          const float* __restrict__ dinv,
                          const unsigned short* __restrict__ y0,
                          unsigned short* __restrict__ y1,
                          unsigned short* __restrict__ y2, int NU, int NI) {
    long t = (long)blockIdx.x * blockDim.x + threadIdx.x;
    int j = (int)(t >> 4);
    if (j >= NI) return;
    int q = (int)(t & 15);
    int i = NU + j;
    int s = irp[j], e = irp[j + 1];
    float di = dinv[i];
    const ushort4* __restrict__ y04 = (const ushort4*)y0;
    const ushort4* __restrict__ y14 = (const ushort4*)y1;
    long p = (long)i * 16 + q;
    ushort4 sv0 = y04[p];  // self y0 row

    float a0x = 0.f, a0y = 0.f, a0z = 0.f, a0w = 0.f;
    float a1x = 0.f, a1y = 0.f, a1z = 0.f, a1w = 0.f;
    for (int k0 = s; k0 < e; k0 += 8) {
        long  off[8];
        float w[8];
#pragma unroll
        for (int jj = 0; jj < 8; ++jj) {
            int k = k0 + jj;
            bool v = (k < e);
            int c = v ? icols[k] : 0;
            off[jj] = (long)c * 16 + q;
            w[jj] = v ? 1.0f : 0.0f;
        }
        ushort4 u0[8], u1[8];
#pragma unroll
        for (int jj = 0; jj < 8; ++jj) { u0[jj] = y04[off[jj]]; u1[jj] = y14[off[jj]]; }
#pragma unroll
        for (int jj = 0; jj < 8; ++jj) {
            a0x += w[jj] * bf2f(u0[jj].x); a0y += w[jj] * bf2f(u0[jj].y);
            a0z += w[jj] * bf2f(u0[jj].z); a0w += w[jj] * bf2f(u0[jj].w);
            a1x += w[jj] * bf2f(u1[jj].x); a1y += w[jj] * bf2f(u1[jj].y);
            a1z += w[jj] * bf2f(u1[jj].z); a1w += w[jj] * bf2f(u1[jj].w);
        }
    }
    float sq = di * di;
    a0x += bf2f(sv0.x); a0y += bf2f(sv0.y); a0z += bf2f(sv0.z); a0w += bf2f(sv0.w);
    ushort4 o1;
    o1.x = f2bf(sq * a0x); o1.y = f2bf(sq * a0y);
    o1.z = f2bf(sq * a0z); o1.w = f2bf(sq * a0w);
    ((ushort4*)y1)[p] = o1;
    // stage 2 self term uses the bf16-rounded y1[i] (identical to memory readback)
    a1x += bf2f(o1.x); a1y += bf2f(o1.y); a1z += bf2f(o1.z); a1w += bf2f(o1.w);
    ushort4 o2;
    o2.x = f2bf(sq * a1x); o2.y = f2bf(sq * a1y);
    o2.z = f2bf(sq * a1z); o2.w = f2bf(sq * a1w);
    ((ushort4*)y2)[p] = o2;
}

// ---- D3: users fused L1+final — one pass over item list, dual gather y1/y2 ----
// y2[u] = d^2 (sum_i y1[i] + y1[u]);  out[u] = (y0+y1+y2)[u]/d + d (sum_i y2[i] + y2[u])
__global__ void d3_kernel(const int* __restrict__ urp, const int* __restrict__ colg,
                          const float* __restrict__ dinv,
                          const unsigned short* __restrict__ y0,
                          const unsigned short* __restrict__ y1,
                          unsigned short* __restrict__ y2,
                          float* __restrict__ out, int NU) {
    long t = (long)blockIdx.x * blockDim.x + threadIdx.x;
    int i = (int)(t >> 4);
    if (i >= NU) return;
    int q = (int)(t & 15);
    int s = urp[i], e = urp[i + 1];
    float di = dinv[i];
    const ushort4* __restrict__ y04 = (const ushort4*)y0;
    const ushort4* __restrict__ y14 = (const ushort4*)y1;
    const ushort4* __restrict__ y24 = (const ushort4*)y2;
    long p = (long)i * 16 + q;
    ushort4 sv0 = y04[p];
    ushort4 sv1 = y14[p];

    float a1x = 0.f, a1y = 0.f, a1z = 0.f, a1w = 0.f;
    float a2x = 0.f, a2y = 0.f, a2z = 0.f, a2w = 0.f;
    for (int k0 = s; k0 < e; k0 += 8) {
        long  off[8];
        float w[8];
#pragma unroll
        for (int jj = 0; jj < 8; ++jj) {
            int k = k0 + jj;
            bool v = (k < e);
            int c = v ? colg[k] : 0;
            off[jj] = (long)c * 16 + q;
            w[jj] = v ? 1.0f : 0.0f;
        }
        ushort4 u1[8], u2[8];
#pragma unroll
        for (int jj = 0; jj < 8; ++jj) { u1[jj] = y14[off[jj]]; u2[jj] = y24[off[jj]]; }
#pragma unroll
        for (int jj = 0; jj < 8; ++jj) {
            a1x += w[jj] * bf2f(u1[jj].x); a1y += w[jj] * bf2f(u1[jj].y);
            a1z += w[jj] * bf2f(u1[jj].z); a1w += w[jj] * bf2f(u1[jj].w);
            a2x += w[jj] * bf2f(u2[jj].x); a2y += w[jj] * bf2f(u2[jj].y);
            a2z += w[jj] * bf2f(u2[jj].z); a2w += w[jj] * bf2f(u2[jj].w);
        }
    }
    float sq = di * di;
    a1x += bf2f(sv1.x); a1y += bf2f(sv1.y); a1z += bf2f(sv1.z); a1w += bf2f(sv1.w);
    ushort4 o2;
    o2.x = f2bf(sq * a1x); o2.y = f2bf(sq * a1y);
    o2.z = f2bf(sq * a1z); o2.w = f2bf(sq * a1w);
    ((ushort4*)y2)[p] = o2;
    a2x += bf2f(o2.x); a2y += bf2f(o2.y); a2z += bf2f(o2.z); a2w += bf2f(o2.w);
    float inv = 1.0f / di;
    float4 o;
    o.x = (bf2f(sv0.x) + bf2f(sv1.x) + bf2f(o2.x)) * inv + di * a2x;
    o.y = (bf2f(sv0.y) + bf2f(sv1.y) + bf2f(o2.y)) * inv + di * a2y;
    o.z = (bf2f(sv0.z) + bf2f(sv1.z) + bf2f(o2.z)) * inv + di * a2z;
    o.w = (bf2f(sv0.w) + bf2f(sv1.w) + bf2f(o2.w)) * inv + di * a2w;
    ((float4*)out)[p] = o;
}

// ---- D4: items final — gather y2[users], write out[items] ----
__global__ void d4_kernel(const int* __restrict__ irp, const int* __restrict__ icols,
                          const float* __restrict__ dinv,
                          const unsigned short* __restrict__ y0,
                          const unsigned short* __restrict__ y1,
                          const unsigned short* __restrict__ y2,
                          float* __restrict__ out, int NU, int NI) {
    long t = (long)blockIdx.x * blockDim.x + threadIdx.x;
    int j = (int)(t >> 4);
    if (j >= NI) return;
    int q = (int)(t & 15);
    int i = NU + j;
    int s = irp[j], e = irp[j + 1];
    float di = dinv[i];
    const ushort4* __restrict__ y04 = (const ushort4*)y0;
    const ushort4* __restrict__ y14 = (const ushort4*)y1;
    const ushort4* __restrict__ y24 = (const ushort4*)y2;
    long p = (long)i * 16 + q;
    ushort4 sv0 = y04[p];
    ushort4 sv1 = y14[p];
    ushort4 sv2 = y24[p];

    float ax = 0.f, ay = 0.f, az = 0.f, aw = 0.f;
    for (int k0 = s; k0 < e; k0 += 8) {
        int   c[8];
        float w[8];
#pragma unroll
        for (int jj = 0; jj < 8; ++jj) {
            int k = k0 + jj;
            bool v = (k < e);
            c[jj] = v ? icols[k] : 0;
            w[jj] = v ? 1.0f : 0.0f;
        }
        ushort4 u[8];
#pragma unroll
        for (int jj = 0; jj < 8; ++jj) u[jj] = y24[(long)c[jj] * 16 + q];
#pragma unroll
        for (int jj = 0; jj < 8; ++jj) {
            ax += w[jj] * bf2f(u[jj].x);
            ay += w[jj] * bf2f(u[jj].y);
            az += w[jj] * bf2f(u[jj].z);
            aw += w[jj] * bf2f(u[jj].w);
        }
    }
    ax += bf2f(sv2.x); ay += bf2f(sv2.y); az += bf2f(sv2.z); aw += bf2f(sv2.w);
    float inv = 1.0f / di;
    float4 o;
    o.x = (bf2f(sv0.x) + bf2f(sv1.x) + bf2f(sv2.x)) * inv + di * ax;
    o.y = (bf2f(sv0.y) + bf2f(sv1.y) + bf2f(sv2.y)) * inv + di * ay;
    o.z = (bf2f(sv0.z) + bf2f(sv1.z) + bf2f(sv2.z)) * inv + di * az;
    o.w = (bf2f(sv0.w) + bf2f(sv1.w) + bf2f(sv2.w)) * inv + di * aw;
    ((float4*)out)[p] = o;
}

extern "C" void kernel_launch(void* const* d_in, const int* in_sizes, int n_in,
                              void* d_out, int out_size, void* d_ws, size_t ws_size,
                              hipStream_t stream) {
    const int*   edge_index = (const int*)d_in[0];   // [2, E]
    const float* user_emb   = (const float*)d_in[1]; // [NU, 64]
    const float* item_emb   = (const float*)d_in[2]; // [NI, 64]
    float* out = (float*)d_out;

    const int  E  = in_sizes[0] / 2;
    const int  Eh = E / 2;             // first half: user rows (sorted), cols = items
    const int  NU = in_sizes[1] / EMB;
    const int  NI = in_sizes[2] / EMB;
    const int  N  = NU + NI;
    const long total = (long)N * EMB;

    const int* row = edge_index;       // [E]
    const int* col = edge_index + E;   // [E]
    const int* rowh = row;             // first Eh: sorted user ids
    const int* colh = col;             // first Eh: item ids (random)

    // workspace layout:
    // urp[NU+1] | degit[NI] | excl[NI] | partials[512] | bcur[512] | irp[NI+1] |
    // cursor[NI] | icols[Eh] | dinv[N] f | y0/y1/y2 [total] bf16 (128B-aligned)
    int*   urp      = (int*)d_ws;
    int*   degit    = urp + (NU + 1);
    int*   excl     = degit + NI;
    int*   partials = excl + NI;
    int*   bcur     = partials + 512;
    int*   irp      = bcur + 512;
    int*   cursor   = irp + (NI + 1);
    int*   icols    = cursor + NI;
    float* dinv     = (float*)(icols + Eh);
    unsigned short* y0 = (unsigned short*)(((uintptr_t)(dinv + N) + 127) & ~(uintptr_t)127);
    unsigned short* y1 = y0 + total;   // total*2 bytes is a multiple of 128
    unsigned short* y2 = y1 + total;
    // pass-A staging (Eh*4B ~4MB) lives in y1's ITEM half: dead until D2 writes
    // y1[items], and D2 runs after pass B has consumed the staging.
    unsigned* staging = (unsigned*)(y1 + (long)NU * EMB);

    hipMemsetAsync(degit, 0, (size_t)NI * sizeof(int), stream);

    // K1: urp + ideg
    int urp_blocks  = (NU + 256) / 256;
    int ideg_blocks = (Eh + 255) / 256;
    k1_kernel<<<urp_blocks + ideg_blocks, 256, 0, stream>>>(row, colh, urp, degit,
                                                            NU, Eh, urp_blocks);

    // K3: scan1 + dinv + y0-init
    int nb_s1 = (NI + 1023) / 1024;              // <= 512
    int nb_dv = (N + 255) / 256;
    int nb_in = (int)((total / 4 + 255) / 256);
    k3_kernel<<<nb_s1 + nb_dv + nb_in, 256, 0, stream>>>(degit, excl, partials,
                                                         urp, dinv, user_emb, item_emb, y0,
                                                         NU, NI, N, (long)NU * EMB, total,
                                                         nb_s1, nb_dv);

    scan2_kernel<<<1, 512, 0, stream>>>(partials, nb_s1);
    scan3_kernel<<<(NI + 1 + 255) / 256, 256, 0, stream>>>(excl, partials, irp, cursor,
                                                           bcur, NI, Eh);

    // Pass A: bucket edges (runs-coalesced staging writes)
    int NB = (NI + BKT_SZ - 1) >> BKT_BITS;      // <= 512
    int nb_pa = (Eh + 1023) / 1024;
    passA_kernel<<<nb_pa, 256, 0, stream>>>(rowh, colh, bcur, staging, Eh, NU, NB);

    // M6: pass B (NB blocks first) || users-L0 (y1[users] from y0[items])
    int nb_us = (int)(((long)NU * 16 + 255) / 256);
    m6_kernel<<<NB + nb_us, 256, 0, stream>>>(staging, irp, cursor, icols, NB, NI,
                                              urp, col, dinv, y0, y1, NU);

    // D2: items L0+L1 (dual gather y0/y1 over user lists) -> y1[items], y2[items]
    int nb_it = (int)(((long)NI * 16 + 255) / 256);
    d2_kernel<<<nb_it, 256, 0, stream>>>(irp, icols, dinv, y0, y1, y2, NU, NI);

    // D3: users L1+final (dual gather y1/y2 over item lists) -> y2[users], out[users]
    d3_kernel<<<nb_us, 256, 0, stream>>>(urp, col, dinv, y0, y1, y2, out, NU);

    // D4: items final (gather y2[users]) -> out[items]
    d4_kernel<<<nb_it, 256, 0, stream>>>(irp, icols, dinv, y0, y1, y2, out, NU, NI);
}

// Round 7
// 531.884 us; speedup vs baseline: 1.1733x; 1.1324x over previous
//
#include <hip/hip_runtime.h>
#include <hip/hip_bf16.h>

#define EMB 64
#define BKT_BITS 10                      // 1024 items per bucket
#define BKT_SZ   (1 << BKT_BITS)
#define NBMAX    256                     // max buckets supported
#define PAD      32                      // ints per padded counter (one 128B line)
#define U_BITS   18                      // NU=200000 < 2^18
#define U_MASK   ((1u << U_BITS) - 1u)

__device__ __forceinline__ float bf2f(unsigned short h) {
    return __uint_as_float(((unsigned)h) << 16);
}
__device__ __forceinline__ unsigned short f2bf(float f) {
    unsigned u = __float_as_uint(f);
    unsigned r = (u + 0x7fffu + ((u >> 16) & 1u)) >> 16;  // RNE
    return (unsigned short)r;
}

// ---- K1: [user section: urp + dinv(users) + y0(users)] U [bucket count] ----
// User blocks: 16 rows each; 17 binary searches give urp + degrees locally
// (no separate urp kernel, no dependency on a degree pass).
// pcount blocks: LDS histogram over buckets -> padded one-line-per-counter
// global adds (~48k total, vs 2M per-edge atomics before).
__global__ void k1_kernel(const int* __restrict__ row, const int* __restrict__ colh,
                          int* __restrict__ urp, float* __restrict__ dinv,
                          const float* __restrict__ ue, unsigned short* __restrict__ y0,
                          int* __restrict__ btotp,
                          int NU, int Eh, int NB, int UB) {
    __shared__ int bound[17];
    __shared__ int hist[NBMAX];
    int t = threadIdx.x;
    if ((int)blockIdx.x < UB) {
        int r0 = blockIdx.x * 16;
        if (t < 17) {
            int r = r0 + t;
            if (r <= NU) {
                int lo = 0, hi = Eh;
                while (lo < hi) {
                    int mid = (lo + hi) >> 1;
                    if (row[mid] < r) lo = mid + 1; else hi = mid;
                }
                bound[t] = lo;
                urp[r] = lo;                    // overlapping writes across blocks: same value
                if (t < 16 && r < NU)
                    dinv[r] = rsqrtf((float)(0) + 0.0f);  // placeholder, fixed below
            }
        }
        __syncthreads();
        // dinv needs bound[t+1]; do it after the barrier
        if (t < 16 && r0 + t < NU)
            dinv[r0 + t] = rsqrtf((float)(bound[t + 1] - bound[t]) + 1.0f);
        long j4 = (long)r0 * 64 + t * 4;
        if (j4 < (long)NU * 64) {
            int rb = t >> 4;                    // row within block
            float sc = rsqrtf((float)(bound[rb + 1] - bound[rb]) + 1.0f);
            float4 v = ((const float4*)ue)[j4 >> 2];
            ushort4 o;
            o.x = f2bf(sc * v.x); o.y = f2bf(sc * v.y);
            o.z = f2bf(sc * v.z); o.w = f2bf(sc * v.w);
            ((ushort4*)y0)[j4 >> 2] = o;
        }
    } else {
        hist[t] = 0;
        if (t + 256 < NBMAX) hist[t + 256] = 0;
        __syncthreads();
        long e0 = (long)(blockIdx.x - UB) * 4096;
#pragma unroll
        for (int k = 0; k < 16; ++k) {
            long e = e0 + k * 256 + t;
            if (e < Eh) atomicAdd(&hist[(colh[e] - NU) >> BKT_BITS], 1);
        }
        __syncthreads();
        if (t < NB && hist[t]) atomicAdd(&btotp[t * PAD], hist[t]);
    }
}

// ---- scanS: bucket totals -> exclusive bases; seed passA cursors ----
__global__ void scanS_kernel(const int* __restrict__ btotp, int* __restrict__ bbase,
                             int* __restrict__ bcurp, int NB, int Eh) {
    __shared__ int sh[256];
    int t = threadIdx.x;
    int v = (t < NB) ? btotp[t * PAD] : 0;
    sh[t] = v;
    __syncthreads();
    for (int off = 1; off < 256; off <<= 1) {
        int u = (t >= off) ? sh[t - off] : 0;
        __syncthreads();
        sh[t] += u;
        __syncthreads();
    }
    if (t < NB) {
        int excl = sh[t] - v;
        bbase[t] = excl;
        bcurp[t * PAD] = excl;
        if (t == NB - 1) bbase[NB] = sh[t];   // == Eh
    }
}

// ---- Pass A: radix-partition edges into item-range buckets ----
// Per-block single reservation per bucket on PADDED counters (191k adds on
// 98 separate lines), packed run writes (item_off<<18 | user).
__global__ void passA_kernel(const int* __restrict__ rowh, const int* __restrict__ colh,
                             int* __restrict__ bcurp, unsigned* __restrict__ staging,
                             int Eh, int NU, int NB) {
    __shared__ int cnt[NBMAX];
    __shared__ int base[NBMAX];
    int t = threadIdx.x;
    cnt[t] = 0;
    if (t + 256 < NBMAX) cnt[t + 256] = 0;
    __syncthreads();
    long cb = (long)blockIdx.x * 1024;
    int b[4], rk[4];
    unsigned pk[4];
#pragma unroll
    for (int j = 0; j < 4; ++j) {
        long e = cb + j * 256 + t;
        if (e < Eh) {
            int u = rowh[e];
            int loc = colh[e] - NU;
            b[j] = loc >> BKT_BITS;
            pk[j] = ((unsigned)(loc & (BKT_SZ - 1)) << U_BITS) | (unsigned)u;
            rk[j] = atomicAdd(&cnt[b[j]], 1);
        } else {
            b[j] = -1;
        }
    }
    __syncthreads();
    if (t < NB) base[t] = cnt[t] ? atomicAdd(&bcurp[t * PAD], cnt[t]) : 0;
    __syncthreads();
#pragma unroll
    for (int j = 0; j < 4; ++j)
        if (b[j] >= 0) staging[base[b[j]] + rk[j]] = pk[j];
}

// ---- Pass B: one 1024-thread block per bucket. All bookkeeping in LDS:  ----
// histogram -> degrees -> prefix scan -> irp + dinv(items) coalesced,     ----
// icols ranks via LDS cursor (ZERO global atomics), y0(items) init fused. ----
__global__ void passB_kernel(const unsigned* __restrict__ staging,
                             const int* __restrict__ bbase,
                             int* __restrict__ irp, int* __restrict__ icols,
                             float* __restrict__ dinv,
                             const float* __restrict__ ie, unsigned short* __restrict__ y0,
                             int NU, int NI, int NB, int Eh) {
    __shared__ int cnt[BKT_SZ];
    __shared__ int sh[BKT_SZ];
    int t = threadIdx.x;
    int b = blockIdx.x;
    int lo = b << BKT_BITS;
    int sb = bbase[b], se = bbase[b + 1];

    cnt[t] = 0;
    __syncthreads();
    for (int k = sb + t; k < se; k += 1024)
        atomicAdd(&cnt[staging[k] >> U_BITS], 1);
    __syncthreads();

    // exclusive scan of the 1024 per-item counts
    sh[t] = cnt[t];
    __syncthreads();
    for (int off = 1; off < 1024; off <<= 1) {
        int v = (t >= off) ? sh[t - off] : 0;
        __syncthreads();
        sh[t] += v;
        __syncthreads();
    }
    int exclv = sh[t] - cnt[t];
    int item = lo + t;
    if (item < NI) {
        irp[item] = sb + exclv;
        dinv[NU + item] = rsqrtf((float)cnt[t] + 1.0f);
    }
    if (b == NB - 1 && t == 0) irp[NI] = Eh;
    __syncthreads();
    sh[t] = exclv;            // becomes the LDS cursor
    __syncthreads();
    for (int k = sb + t; k < se; k += 1024) {
        unsigned v = staging[k];
        int io = (int)(v >> U_BITS);
        int r = atomicAdd(&sh[io], 1);
        icols[sb + r] = (int)(v & U_MASK);
    }

    // y0(items) init for this bucket (degrees live in cnt[])
    for (int m = t; m < BKT_SZ * 16; m += 1024) {
        int it = lo + (m >> 4);
        if (it >= NI) break;
        float sc = rsqrtf((float)cnt[m >> 4] + 1.0f);
        float4 v = ((const float4*)ie)[(long)it * 16 + (m & 15)];
        ushort4 o;
        o.x = f2bf(sc * v.x); o.y = f2bf(sc * v.y);
        o.z = f2bf(sc * v.z); o.w = f2bf(sc * v.w);
        ((ushort4*)y0)[((long)NU + it) * 16 + (m & 15)] = o;
    }
}

// ---- users L0: y1[users] = d^2 (sum y0[items] + y0[u]) ----
__global__ void ul0_kernel(const int* __restrict__ urp, const int* __restrict__ colg,
                           const float* __restrict__ dinv,
                           const unsigned short* __restrict__ y0,
                           unsigned short* __restrict__ y1, int NU) {
    long t = (long)blockIdx.x * blockDim.x + threadIdx.x;
    int i = (int)(t >> 4);
    if (i >= NU) return;
    int q = (int)(t & 15);
    int s = urp[i], e = urp[i + 1];
    float di = dinv[i];
    const ushort4* __restrict__ y04 = (const ushort4*)y0;
    long p = (long)i * 16 + q;
    ushort4 sv = y04[p];

    float ax = 0.f, ay = 0.f, az = 0.f, aw = 0.f;
    for (int k0 = s; k0 < e; k0 += 8) {
        int   c[8];
        float w[8];
#pragma unroll
        for (int j = 0; j < 8; ++j) {
            int k = k0 + j;
            bool v = (k < e);
            c[j] = v ? colg[k] : 0;
            w[j] = v ? 1.0f : 0.0f;
        }
        ushort4 u[8];
#pragma unroll
        for (int j = 0; j < 8; ++j) u[j] = y04[(long)c[j] * 16 + q];
#pragma unroll
        for (int j = 0; j < 8; ++j) {
            ax += w[j] * bf2f(u[j].x);
            ay += w[j] * bf2f(u[j].y);
            az += w[j] * bf2f(u[j].z);
            aw += w[j] * bf2f(u[j].w);
        }
    }
    ax += bf2f(sv.x); ay += bf2f(sv.y); az += bf2f(sv.z); aw += bf2f(sv.w);
    float sq = di * di;
    ushort4 o;
    o.x = f2bf(sq * ax); o.y = f2bf(sq * ay); o.z = f2bf(sq * az); o.w = f2bf(sq * aw);
    ((ushort4*)y1)[p] = o;
}

// ---- D2: items fused L0+L1 — one pass over user list, dual gather y0/y1 ----
__global__ void d2_kernel(const int* __restrict__ irp, const int* __restrict__ icols,
                          const float* __restrict__ dinv,
                          const unsigned short* __restrict__ y0,
                          unsigned short* __restrict__ y1,
                          unsigned short* __restrict__ y2, int NU, int NI) {
    long t = (long)blockIdx.x * blockDim.x + threadIdx.x;
    int j = (int)(t >> 4);
    if (j >= NI) return;
    int q = (int)(t & 15);
    int i = NU + j;
    int s = irp[j], e = irp[j + 1];
    float di = dinv[i];
    const ushort4* __restrict__ y04 = (const ushort4*)y0;
    const ushort4* __restrict__ y14 = (const ushort4*)y1;
    long p = (long)i * 16 + q;
    ushort4 sv0 = y04[p];

    float a0x = 0.f, a0y = 0.f, a0z = 0.f, a0w = 0.f;
    float a1x = 0.f, a1y = 0.f, a1z = 0.f, a1w = 0.f;
    for (int k0 = s; k0 < e; k0 += 8) {
        long  off[8];
        float w[8];
#pragma unroll
        for (int jj = 0; jj < 8; ++jj) {
            int k = k0 + jj;
            bool v = (k < e);
            int c = v ? icols[k] : 0;
            off[jj] = (long)c * 16 + q;
            w[jj] = v ? 1.0f : 0.0f;
        }
        ushort4 u0[8], u1[8];
#pragma unroll
        for (int jj = 0; jj < 8; ++jj) { u0[jj] = y04[off[jj]]; u1[jj] = y14[off[jj]]; }
#pragma unroll
        for (int jj = 0; jj < 8; ++jj) {
            a0x += w[jj] * bf2f(u0[jj].x); a0y += w[jj] * bf2f(u0[jj].y);
            a0z += w[jj] * bf2f(u0[jj].z); a0w += w[jj] * bf2f(u0[jj].w);
            a1x += w[jj] * bf2f(u1[jj].x); a1y += w[jj] * bf2f(u1[jj].y);
            a1z += w[jj] * bf2f(u1[jj].z); a1w += w[jj] * bf2f(u1[jj].w);
        }
    }
    float sq = di * di;
    a0x += bf2f(sv0.x); a0y += bf2f(sv0.y); a0z += bf2f(sv0.z); a0w += bf2f(sv0.w);
    ushort4 o1;
    o1.x = f2bf(sq * a0x); o1.y = f2bf(sq * a0y);
    o1.z = f2bf(sq * a0z); o1.w = f2bf(sq * a0w);
    ((ushort4*)y1)[p] = o1;
    a1x += bf2f(o1.x); a1y += bf2f(o1.y); a1z += bf2f(o1.z); a1w += bf2f(o1.w);
    ushort4 o2;
    o2.x = f2bf(sq * a1x); o2.y = f2bf(sq * a1y);
    o2.z = f2bf(sq * a1z); o2.w = f2bf(sq * a1w);
    ((ushort4*)y2)[p] = o2;
}

// ---- D3: users fused L1+final — dual gather y1/y2 over item lists ----
__global__ void d3_kernel(const int* __restrict__ urp, const int* __restrict__ colg,
                          const float* __restrict__ dinv,
                          const unsigned short* __restrict__ y0,
                          const unsigned short* __restrict__ y1,
                          unsigned short* __restrict__ y2,
                          float* __restrict__ out, int NU) {
    long t = (long)blockIdx.x * blockDim.x + threadIdx.x;
    int i = (int)(t >> 4);
    if (i >= NU) return;
    int q = (int)(t & 15);
    int s = urp[i], e = urp[i + 1];
    float di = dinv[i];
    const ushort4* __restrict__ y04 = (const ushort4*)y0;
    const ushort4* __restrict__ y14 = (const ushort4*)y1;
    const ushort4* __restrict__ y24 = (const ushort4*)y2;
    long p = (long)i * 16 + q;
    ushort4 sv0 = y04[p];
    ushort4 sv1 = y14[p];

    float a1x = 0.f, a1y = 0.f, a1z = 0.f, a1w = 0.f;
    float a2x = 0.f, a2y = 0.f, a2z = 0.f, a2w = 0.f;
    for (int k0 = s; k0 < e; k0 += 8) {
        long  off[8];
        float w[8];
#pragma unroll
        for (int jj = 0; jj < 8; ++jj) {
            int k = k0 + jj;
            bool v = (k < e);
            int c = v ? colg[k] : 0;
            off[jj] = (long)c * 16 + q;
            w[jj] = v ? 1.0f : 0.0f;
        }
        ushort4 u1[8], u2[8];
#pragma unroll
        for (int jj = 0; jj < 8; ++jj) { u1[jj] = y14[off[jj]]; u2[jj] = y24[off[jj]]; }
#pragma unroll
        for (int jj = 0; jj < 8; ++jj) {
            a1x += w[jj] * bf2f(u1[jj].x); a1y += w[jj] * bf2f(u1[jj].y);
            a1z += w[jj] * bf2f(u1[jj].z); a1w += w[jj] * bf2f(u1[jj].w);
            a2x += w[jj] * bf2f(u2[jj].x); a2y += w[jj] * bf2f(u2[jj].y);
            a2z += w[jj] * bf2f(u2[jj].z); a2w += w[jj] * bf2f(u2[jj].w);
        }
    }
    float sq = di * di;
    a1x += bf2f(sv1.x); a1y += bf2f(sv1.y); a1z += bf2f(sv1.z); a1w += bf2f(sv1.w);
    ushort4 o2;
    o2.x = f2bf(sq * a1x); o2.y = f2bf(sq * a1y);
    o2.z = f2bf(sq * a1z); o2.w = f2bf(sq * a1w);
    ((ushort4*)y2)[p] = o2;
    a2x += bf2f(o2.x); a2y += bf2f(o2.y); a2z += bf2f(o2.z); a2w += bf2f(o2.w);
    float inv = 1.0f / di;
    float4 o;
    o.x = (bf2f(sv0.x) + bf2f(sv1.x) + bf2f(o2.x)) * inv + di * a2x;
    o.y = (bf2f(sv0.y) + bf2f(sv1.y) + bf2f(o2.y)) * inv + di * a2y;
    o.z = (bf2f(sv0.z) + bf2f(sv1.z) + bf2f(o2.z)) * inv + di * a2z;
    o.w = (bf2f(sv0.w) + bf2f(sv1.w) + bf2f(o2.w)) * inv + di * a2w;
    ((float4*)out)[p] = o;
}

// ---- D4: items final — gather y2[users], write out[items] ----
__global__ void d4_kernel(const int* __restrict__ irp, const int* __restrict__ icols,
                          const float* __restrict__ dinv,
                          const unsigned short* __restrict__ y0,
                          const unsigned short* __restrict__ y1,
                          const unsigned short* __restrict__ y2,
                          float* __restrict__ out, int NU, int NI) {
    long t = (long)blockIdx.x * blockDim.x + threadIdx.x;
    int j = (int)(t >> 4);
    if (j >= NI) return;
    int q = (int)(t & 15);
    int i = NU + j;
    int s = irp[j], e = irp[j + 1];
    float di = dinv[i];
    const ushort4* __restrict__ y04 = (const ushort4*)y0;
    const ushort4* __restrict__ y14 = (const ushort4*)y1;
    const ushort4* __restrict__ y24 = (const ushort4*)y2;
    long p = (long)i * 16 + q;
    ushort4 sv0 = y04[p];
    ushort4 sv1 = y14[p];
    ushort4 sv2 = y24[p];

    float ax = 0.f, ay = 0.f, az = 0.f, aw = 0.f;
    for (int k0 = s; k0 < e; k0 += 8) {
        int   c[8];
        float w[8];
#pragma unroll
        for (int jj = 0; jj < 8; ++jj) {
            int k = k0 + jj;
            bool v = (k < e);
            c[jj] = v ? icols[k] : 0;
            w[jj] = v ? 1.0f : 0.0f;
        }
        ushort4 u[8];
#pragma unroll
        for (int jj = 0; jj < 8; ++jj) u[jj] = y24[(long)c[jj] * 16 + q];
#pragma unroll
        for (int jj = 0; jj < 8; ++jj) {
            ax += w[jj] * bf2f(u[jj].x);
            ay += w[jj] * bf2f(u[jj].y);
            az += w[jj] * bf2f(u[jj].z);
            aw += w[jj] * bf2f(u[jj].w);
        }
    }
    ax += bf2f(sv2.x); ay += bf2f(sv2.y); az += bf2f(sv2.z); aw += bf2f(sv2.w);
    float inv = 1.0f / di;
    float4 o;
    o.x = (bf2f(sv0.x) + bf2f(sv1.x) + bf2f(sv2.x)) * inv + di * ax;
    o.y = (bf2f(sv0.y) + bf2f(sv1.y) + bf2f(sv2.y)) * inv + di * ay;
    o.z = (bf2f(sv0.z) + bf2f(sv1.z) + bf2f(sv2.z)) * inv + di * az;
    o.w = (bf2f(sv0.w) + bf2f(sv1.w) + bf2f(sv2.w)) * inv + di * aw;
    ((float4*)out)[p] = o;
}

extern "C" void kernel_launch(void* const* d_in, const int* in_sizes, int n_in,
                              void* d_out, int out_size, void* d_ws, size_t ws_size,
                              hipStream_t stream) {
    const int*   edge_index = (const int*)d_in[0];   // [2, E]
    const float* user_emb   = (const float*)d_in[1]; // [NU, 64]
    const float* item_emb   = (const float*)d_in[2]; // [NI, 64]
    float* out = (float*)d_out;

    const int  E  = in_sizes[0] / 2;
    const int  Eh = E / 2;             // first half: user rows (sorted), cols = items
    const int  NU = in_sizes[1] / EMB;
    const int  NI = in_sizes[2] / EMB;
    const int  N  = NU + NI;
    const long total = (long)N * EMB;

    const int* row = edge_index;       // [E]
    const int* col = edge_index + E;   // [E]
    const int* rowh = row;             // first Eh: sorted user ids
    const int* colh = col;             // first Eh: item ids (random)

    // workspace layout:
    // urp[NU+1] | btotp[NBMAX*PAD] | bcurp[NBMAX*PAD] | bbase[NBMAX+1] |
    // irp[NI+1] | icols[Eh] | dinv[N] f | y0/y1/y2 [total] bf16 (128B-aligned)
    int*   urp   = (int*)d_ws;
    int*   btotp = urp + (NU + 1);
    int*   bcurp = btotp + NBMAX * PAD;
    int*   bbase = bcurp + NBMAX * PAD;
    int*   irp   = bbase + (NBMAX + 1);
    int*   icols = irp + (NI + 1);
    float* dinv  = (float*)(icols + Eh);
    unsigned short* y0 = (unsigned short*)(((uintptr_t)(dinv + N) + 127) & ~(uintptr_t)127);
    unsigned short* y1 = y0 + total;   // total*2 bytes is a multiple of 128
    unsigned short* y2 = y1 + total;
    // pass-A staging (Eh*4B ~8MB) lives in y1's ITEM half (~12.8MB): dead until
    // D2 writes y1[items], and D2 runs after passB has consumed the staging.
    unsigned* staging = (unsigned*)(y1 + (long)NU * EMB);

    const int NB = (NI + BKT_SZ - 1) >> BKT_BITS;   // 98 for NI=100k (<= NBMAX)

    hipMemsetAsync(btotp, 0, (size_t)NBMAX * PAD * sizeof(int), stream);

    // K1: [users: urp + dinv + y0] U [bucket counts]
    int UB = (NU + 15) / 16;
    int PC = (Eh + 4095) / 4096;
    k1_kernel<<<UB + PC, 256, 0, stream>>>(row, colh, urp, dinv, user_emb, y0,
                                           btotp, NU, Eh, NB, UB);

    // scanS: bucket bases + cursor seeds
    scanS_kernel<<<1, 256, 0, stream>>>(btotp, bbase, bcurp, NB, Eh);

    // Pass A: bucket partition (padded block-level reservations only)
    passA_kernel<<<(Eh + 1023) / 1024, 256, 0, stream>>>(rowh, colh, bcurp, staging,
                                                         Eh, NU, NB);

    // Pass B: icols + irp + dinv(items) + y0(items) — zero global atomics
    passB_kernel<<<NB, 1024, 0, stream>>>(staging, bbase, irp, icols, dinv,
                                          item_emb, y0, NU, NI, NB, Eh);

    // users L0: y1[users]
    int nb_us = (int)(((long)NU * 16 + 255) / 256);
    ul0_kernel<<<nb_us, 256, 0, stream>>>(urp, col, dinv, y0, y1, NU);

    // D2: items L0+L1 (dual gather y0/y1) -> y1[items], y2[items]
    int nb_it = (int)(((long)NI * 16 + 255) / 256);
    d2_kernel<<<nb_it, 256, 0, stream>>>(irp, icols, dinv, y0, y1, y2, NU, NI);

    // D3: users L1+final (dual gather y1/y2) -> y2[users], out[users]
    d3_kernel<<<nb_us, 256, 0, stream>>>(urp, col, dinv, y0, y1, y2, out, NU);

    // D4: items final (gather y2[users]) -> out[items]
    d4_kernel<<<nb_it, 256, 0, stream>>>(irp, icols, dinv, y0, y1, y2, out, NU, NI);
}

// Round 8
// 530.006 us; speedup vs baseline: 1.1775x; 1.0035x over previous
//
#include <hip/hip_runtime.h>
#include <hip/hip_bf16.h>

#define EMB 64
#define BKT_BITS 10                      // 1024 items per bucket
#define BKT_SZ   (1 << BKT_BITS)
#define NBMAX    256                     // max buckets supported
#define PAD      32                      // ints per padded counter (one 128B line)
#define U_BITS   18                      // NU=200000 < 2^18
#define U_MASK   ((1u << U_BITS) - 1u)

__device__ __forceinline__ float bf2f(unsigned short h) {
    return __uint_as_float(((unsigned)h) << 16);
}
__device__ __forceinline__ unsigned short f2bf(float f) {
    unsigned u = __float_as_uint(f);
    unsigned r = (u + 0x7fffu + ((u >> 16) & 1u)) >> 16;  // RNE
    return (unsigned short)r;
}
// packed bf16-pair helpers: p = lo | hi<<16
__device__ __forceinline__ float bflo(unsigned p) { return __uint_as_float(p << 16); }
__device__ __forceinline__ float bfhi(unsigned p) { return __uint_as_float(p & 0xffff0000u); }
__device__ __forceinline__ unsigned pack2(float a, float b) {
    return (unsigned)f2bf(a) | ((unsigned)f2bf(b) << 16);
}

// ---- K1: [user section: urp + dinv(users) + y0u into yu01] U [bucket count] ----
// yu01 layout: per user row 256B = 16 chunks of 16B; chunk q = [y0 elems 4q..4q+3 | y1 elems 4q..4q+3]
__global__ void k1_kernel(const int* __restrict__ row, const int* __restrict__ colh,
                          int* __restrict__ urp, float* __restrict__ dinv,
                          const float* __restrict__ ue, unsigned short* __restrict__ yu01,
                          int* __restrict__ btotp,
                          int NU, int Eh, int NB, int UB) {
    __shared__ int bound[17];
    __shared__ int hist[NBMAX];
    int t = threadIdx.x;
    if ((int)blockIdx.x < UB) {
        int r0 = blockIdx.x * 16;
        if (t < 17) {
            int r = r0 + t;
            if (r <= NU) {
                int lo = 0, hi = Eh;
                while (lo < hi) {
                    int mid = (lo + hi) >> 1;
                    if (row[mid] < r) lo = mid + 1; else hi = mid;
                }
                bound[t] = lo;
                urp[r] = lo;                    // overlapping writes across blocks: same value
            }
        }
        __syncthreads();
        if (t < 16 && r0 + t < NU)
            dinv[r0 + t] = rsqrtf((float)(bound[t + 1] - bound[t]) + 1.0f);
        long j4 = (long)r0 * 64 + t * 4;        // 4 consecutive elements
        if (j4 < (long)NU * 64) {
            int rb = t >> 4;                    // row within block
            int q  = t & 15;                    // chunk within row
            float sc = rsqrtf((float)(bound[rb + 1] - bound[rb]) + 1.0f);
            float4 v = ((const float4*)ue)[j4 >> 2];
            ushort4 o;
            o.x = f2bf(sc * v.x); o.y = f2bf(sc * v.y);
            o.z = f2bf(sc * v.z); o.w = f2bf(sc * v.w);
            // y0-half of chunk q of row r0+rb
            ((ushort4*)yu01)[((long)(r0 + rb) * 16 + q) * 2 + 0] = o;
        }
    } else {
        hist[t] = 0;
        __syncthreads();
        long e0 = (long)(blockIdx.x - UB) * 4096;
#pragma unroll
        for (int k = 0; k < 16; ++k) {
            long e = e0 + k * 256 + t;
            if (e < Eh) atomicAdd(&hist[(colh[e] - NU) >> BKT_BITS], 1);
        }
        __syncthreads();
        if (t < NB && hist[t]) atomicAdd(&btotp[t * PAD], hist[t]);
    }
}

// ---- scanS: bucket totals -> exclusive bases; seed passA cursors ----
__global__ void scanS_kernel(const int* __restrict__ btotp, int* __restrict__ bbase,
                             int* __restrict__ bcurp, int NB, int Eh) {
    __shared__ int sh[256];
    int t = threadIdx.x;
    int v = (t < NB) ? btotp[t * PAD] : 0;
    sh[t] = v;
    __syncthreads();
    for (int off = 1; off < 256; off <<= 1) {
        int u = (t >= off) ? sh[t - off] : 0;
        __syncthreads();
        sh[t] += u;
        __syncthreads();
    }
    if (t < NB) {
        int excl = sh[t] - v;
        bbase[t] = excl;
        bcurp[t * PAD] = excl;
        if (t == NB - 1) bbase[NB] = sh[t];   // == Eh
    }
}

// ---- Pass A: radix-partition edges into item-range buckets ----
__global__ void passA_kernel(const int* __restrict__ rowh, const int* __restrict__ colh,
                             int* __restrict__ bcurp, unsigned* __restrict__ staging,
                             int Eh, int NU, int NB) {
    __shared__ int cnt[NBMAX];
    __shared__ int base[NBMAX];
    int t = threadIdx.x;
    cnt[t] = 0;
    __syncthreads();
    long cb = (long)blockIdx.x * 1024;
    int b[4], rk[4];
    unsigned pk[4];
#pragma unroll
    for (int j = 0; j < 4; ++j) {
        long e = cb + j * 256 + t;
        if (e < Eh) {
            int u = rowh[e];
            int loc = colh[e] - NU;
            b[j] = loc >> BKT_BITS;
            pk[j] = ((unsigned)(loc & (BKT_SZ - 1)) << U_BITS) | (unsigned)u;
            rk[j] = atomicAdd(&cnt[b[j]], 1);
        } else {
            b[j] = -1;
        }
    }
    __syncthreads();
    if (t < NB) base[t] = cnt[t] ? atomicAdd(&bcurp[t * PAD], cnt[t]) : 0;
    __syncthreads();
#pragma unroll
    for (int j = 0; j < 4; ++j)
        if (b[j] >= 0) staging[base[b[j]] + rk[j]] = pk[j];
}

// ---- Pass B: one 1024-thread block per bucket; zero global atomics ----
// irp + dinv(items) + icols + y0i (item-local, plain 128B rows) init.
__global__ void passB_kernel(const unsigned* __restrict__ staging,
                             const int* __restrict__ bbase,
                             int* __restrict__ irp, int* __restrict__ icols,
                             float* __restrict__ dinv,
                             const float* __restrict__ ie, unsigned short* __restrict__ y0i,
                             int NU, int NI, int NB, int Eh) {
    __shared__ int cnt[BKT_SZ];
    __shared__ int sh[BKT_SZ];
    int t = threadIdx.x;
    int b = blockIdx.x;
    int lo = b << BKT_BITS;
    int sb = bbase[b], se = bbase[b + 1];

    cnt[t] = 0;
    __syncthreads();
    for (int k = sb + t; k < se; k += 1024)
        atomicAdd(&cnt[staging[k] >> U_BITS], 1);
    __syncthreads();

    sh[t] = cnt[t];
    __syncthreads();
    for (int off = 1; off < 1024; off <<= 1) {
        int v = (t >= off) ? sh[t - off] : 0;
        __syncthreads();
        sh[t] += v;
        __syncthreads();
    }
    int exclv = sh[t] - cnt[t];
    int item = lo + t;
    if (item < NI) {
        irp[item] = sb + exclv;
        dinv[NU + item] = rsqrtf((float)cnt[t] + 1.0f);
    }
    if (b == NB - 1 && t == 0) irp[NI] = Eh;
    __syncthreads();
    sh[t] = exclv;            // LDS cursor
    __syncthreads();
    for (int k = sb + t; k < se; k += 1024) {
        unsigned v = staging[k];
        int io = (int)(v >> U_BITS);
        int r = atomicAdd(&sh[io], 1);
        icols[sb + r] = (int)(v & U_MASK);
    }

    // y0i init for this bucket (degrees in cnt[])
    for (int m = t; m < BKT_SZ * 16; m += 1024) {
        int it = lo + (m >> 4);
        if (it >= NI) break;
        float sc = rsqrtf((float)cnt[m >> 4] + 1.0f);
        float4 v = ((const float4*)ie)[(long)it * 16 + (m & 15)];
        ushort4 o;
        o.x = f2bf(sc * v.x); o.y = f2bf(sc * v.y);
        o.z = f2bf(sc * v.z); o.w = f2bf(sc * v.w);
        ((ushort4*)y0i)[(long)it * 16 + (m & 15)] = o;
    }
}

// ---- users L0: y1u = d^2 (sum y0i[neighbors] + y0u) -> y1-half of yu01 ----
__global__ void ul0_kernel(const int* __restrict__ urp, const int* __restrict__ colg,
                           const float* __restrict__ dinv,
                           const unsigned short* __restrict__ y0i,
                           unsigned short* __restrict__ yu01, int NU) {
    long t = (long)blockIdx.x * blockDim.x + threadIdx.x;
    int i = (int)(t >> 4);
    if (i >= NU) return;
    int q = (int)(t & 15);
    int s = urp[i], e = urp[i + 1];
    float di = dinv[i];
    // shifted pointer: global item id c (>=NU) indexes item-local y0i directly
    const ushort4* __restrict__ y0is = (const ushort4*)y0i - (long)NU * 16;
    ushort4 sv = ((const ushort4*)yu01)[((long)i * 16 + q) * 2 + 0];  // self y0u

    float ax = 0.f, ay = 0.f, az = 0.f, aw = 0.f;
    for (int k0 = s; k0 < e; k0 += 8) {
        int   c[8];
        float w[8];
#pragma unroll
        for (int j = 0; j < 8; ++j) {
            int k = k0 + j;
            bool v = (k < e);
            c[j] = v ? colg[k] : NU;
            w[j] = v ? 1.0f : 0.0f;
        }
        ushort4 u[8];
#pragma unroll
        for (int j = 0; j < 8; ++j) u[j] = y0is[(long)c[j] * 16 + q];
#pragma unroll
        for (int j = 0; j < 8; ++j) {
            ax += w[j] * bf2f(u[j].x);
            ay += w[j] * bf2f(u[j].y);
            az += w[j] * bf2f(u[j].z);
            aw += w[j] * bf2f(u[j].w);
        }
    }
    ax += bf2f(sv.x); ay += bf2f(sv.y); az += bf2f(sv.z); aw += bf2f(sv.w);
    float sq = di * di;
    ushort4 o;
    o.x = f2bf(sq * ax); o.y = f2bf(sq * ay); o.z = f2bf(sq * az); o.w = f2bf(sq * aw);
    ((ushort4*)yu01)[((long)i * 16 + q) * 2 + 1] = o;  // y1-half
}

// ---- D2: items L0+L1 — ONE 16B gather per edge gives y0u AND y1u chunks ----
// writes yi12 chunk = [y1i pair | y2i pair] as one 16B store
__global__ void d2_kernel(const int* __restrict__ irp, const int* __restrict__ icols,
                          const float* __restrict__ dinv,
                          const unsigned short* __restrict__ yu01,
                          const unsigned short* __restrict__ y0i,
                          unsigned short* __restrict__ yi12, int NU, int NI) {
    long t = (long)blockIdx.x * blockDim.x + threadIdx.x;
    int j = (int)(t >> 4);
    if (j >= NI) return;
    int q = (int)(t & 15);
    int s = irp[j], e = irp[j + 1];
    float di = dinv[NU + j];
    const uint4* __restrict__ yu = (const uint4*)yu01;
    ushort4 sv0 = ((const ushort4*)y0i)[(long)j * 16 + q];  // self y0i chunk

    float a0x = 0.f, a0y = 0.f, a0z = 0.f, a0w = 0.f;
    float a1x = 0.f, a1y = 0.f, a1z = 0.f, a1w = 0.f;
    for (int k0 = s; k0 < e; k0 += 8) {
        int   off[8];
        float w[8];
#pragma unroll
        for (int jj = 0; jj < 8; ++jj) {
            int k = k0 + jj;
            bool v = (k < e);
            int c = v ? icols[k] : 0;
            off[jj] = c * 16 + q;
            w[jj] = v ? 1.0f : 0.0f;
        }
        uint4 u[8];
#pragma unroll
        for (int jj = 0; jj < 8; ++jj) u[jj] = yu[off[jj]];
#pragma unroll
        for (int jj = 0; jj < 8; ++jj) {
            a0x += w[jj] * bflo(u[jj].x); a0y += w[jj] * bfhi(u[jj].x);
            a0z += w[jj] * bflo(u[jj].y); a0w += w[jj] * bfhi(u[jj].y);
            a1x += w[jj] * bflo(u[jj].z); a1y += w[jj] * bfhi(u[jj].z);
            a1z += w[jj] * bflo(u[jj].w); a1w += w[jj] * bfhi(u[jj].w);
        }
    }
    float sq = di * di;
    a0x += bf2f(sv0.x); a0y += bf2f(sv0.y); a0z += bf2f(sv0.z); a0w += bf2f(sv0.w);
    unsigned o1x = pack2(sq * a0x, sq * a0y);
    unsigned o1y = pack2(sq * a0z, sq * a0w);
    // stage-2 self term uses the bf16-rounded y1i (identical to memory readback)
    a1x += bflo(o1x); a1y += bfhi(o1x); a1z += bflo(o1y); a1w += bfhi(o1y);
    unsigned o2x = pack2(sq * a1x, sq * a1y);
    unsigned o2y = pack2(sq * a1z, sq * a1w);
    uint4 o; o.x = o1x; o.y = o1y; o.z = o2x; o.w = o2y;
    ((uint4*)yi12)[(long)j * 16 + q] = o;
}

// ---- D3: users L1+final — ONE 16B gather per edge gives y1i AND y2i chunks ----
__global__ void d3_kernel(const int* __restrict__ urp, const int* __restrict__ colg,
                          const float* __restrict__ dinv,
                          const unsigned short* __restrict__ yu01,
                          const unsigned short* __restrict__ yi12,
                          unsigned short* __restrict__ y2u,
                          float* __restrict__ out, int NU) {
    long t = (long)blockIdx.x * blockDim.x + threadIdx.x;
    int i = (int)(t >> 4);
    if (i >= NU) return;
    int q = (int)(t & 15);
    int s = urp[i], e = urp[i + 1];
    float di = dinv[i];
    // shifted: global item id c indexes item-local yi12 directly
    const uint4* __restrict__ yis = (const uint4*)yi12 - (long)NU * 16;
    uint4 su = ((const uint4*)yu01)[(long)i * 16 + q];  // [y0u pair2 | y1u pair2]

    float a1x = 0.f, a1y = 0.f, a1z = 0.f, a1w = 0.f;
    float a2x = 0.f, a2y = 0.f, a2z = 0.f, a2w = 0.f;
    for (int k0 = s; k0 < e; k0 += 8) {
        int   off[8];
        float w[8];
#pragma unroll
        for (int jj = 0; jj < 8; ++jj) {
            int k = k0 + jj;
            bool v = (k < e);
            int c = v ? colg[k] : NU;
            off[jj] = c * 16 + q;
            w[jj] = v ? 1.0f : 0.0f;
        }
        uint4 u[8];
#pragma unroll
        for (int jj = 0; jj < 8; ++jj) u[jj] = yis[(long)off[jj]];
#pragma unroll
        for (int jj = 0; jj < 8; ++jj) {
            a1x += w[jj] * bflo(u[jj].x); a1y += w[jj] * bfhi(u[jj].x);
            a1z += w[jj] * bflo(u[jj].y); a1w += w[jj] * bfhi(u[jj].y);
            a2x += w[jj] * bflo(u[jj].z); a2y += w[jj] * bfhi(u[jj].z);
            a2z += w[jj] * bflo(u[jj].w); a2w += w[jj] * bfhi(u[jj].w);
        }
    }
    float sq = di * di;
    // self y1u = su.z/su.w
    a1x += bflo(su.z); a1y += bfhi(su.z); a1z += bflo(su.w); a1w += bfhi(su.w);
    unsigned o2x = pack2(sq * a1x, sq * a1y);
    unsigned o2y = pack2(sq * a1z, sq * a1w);
    ((uint2*)y2u)[(long)i * 16 + q] = make_uint2(o2x, o2y);
    a2x += bflo(o2x); a2y += bfhi(o2x); a2z += bflo(o2y); a2w += bfhi(o2y);
    float inv = 1.0f / di;
    float4 o;
    o.x = (bflo(su.x) + bflo(su.z) + bflo(o2x)) * inv + di * a2x;
    o.y = (bfhi(su.x) + bfhi(su.z) + bfhi(o2x)) * inv + di * a2y;
    o.z = (bflo(su.y) + bflo(su.w) + bflo(o2y)) * inv + di * a2z;
    o.w = (bfhi(su.y) + bfhi(su.w) + bfhi(o2y)) * inv + di * a2w;
    ((float4*)out)[(long)i * 16 + q] = o;
}

// ---- D4: items final — gather y2u[users], write out[items] ----
__global__ void d4_kernel(const int* __restrict__ irp, const int* __restrict__ icols,
                          const float* __restrict__ dinv,
                          const unsigned short* __restrict__ y0i,
                          const unsigned short* __restrict__ yi12,
                          const unsigned short* __restrict__ y2u,
                          float* __restrict__ out, int NU, int NI) {
    long t = (long)blockIdx.x * blockDim.x + threadIdx.x;
    int j = (int)(t >> 4);
    if (j >= NI) return;
    int q = (int)(t & 15);
    int s = irp[j], e = irp[j + 1];
    float di = dinv[NU + j];
    const ushort4* __restrict__ y2u4 = (const ushort4*)y2u;
    ushort4 sv0 = ((const ushort4*)y0i)[(long)j * 16 + q];
    uint4   si  = ((const uint4*)yi12)[(long)j * 16 + q];   // [y1i pair2 | y2i pair2]

    float ax = 0.f, ay = 0.f, az = 0.f, aw = 0.f;
    for (int k0 = s; k0 < e; k0 += 8) {
        int   c[8];
        float w[8];
#pragma unroll
        for (int jj = 0; jj < 8; ++jj) {
            int k = k0 + jj;
            bool v = (k < e);
            c[jj] = v ? icols[k] : 0;
            w[jj] = v ? 1.0f : 0.0f;
        }
        ushort4 u[8];
#pragma unroll
        for (int jj = 0; jj < 8; ++jj) u[jj] = y2u4[(long)c[jj] * 16 + q];
#pragma unroll
        for (int jj = 0; jj < 8; ++jj) {
            ax += w[jj] * bf2f(u[jj].x);
            ay += w[jj] * bf2f(u[jj].y);
            az += w[jj] * bf2f(u[jj].z);
            aw += w[jj] * bf2f(u[jj].w);
        }
    }
    // self y2i = si.z/si.w
    ax += bflo(si.z); ay += bfhi(si.z); az += bflo(si.w); aw += bfhi(si.w);
    float inv = 1.0f / di;
    float4 o;
    o.x = (bf2f(sv0.x) + bflo(si.x) + bflo(si.z)) * inv + di * ax;
    o.y = (bf2f(sv0.y) + bfhi(si.x) + bfhi(si.z)) * inv + di * ay;
    o.z = (bf2f(sv0.z) + bflo(si.y) + bflo(si.w)) * inv + di * az;
    o.w = (bf2f(sv0.w) + bfhi(si.y) + bfhi(si.w)) * inv + di * aw;
    ((float4*)out)[((long)NU + j) * 16 + q] = o;
}

extern "C" void kernel_launch(void* const* d_in, const int* in_sizes, int n_in,
                              void* d_out, int out_size, void* d_ws, size_t ws_size,
                              hipStream_t stream) {
    const int*   edge_index = (const int*)d_in[0];   // [2, E]
    const float* user_emb   = (const float*)d_in[1]; // [NU, 64]
    const float* item_emb   = (const float*)d_in[2]; // [NI, 64]
    float* out = (float*)d_out;

    const int  E  = in_sizes[0] / 2;
    const int  Eh = E / 2;             // first half: user rows (sorted), cols = items
    const int  NU = in_sizes[1] / EMB;
    const int  NI = in_sizes[2] / EMB;
    const int  N  = NU + NI;

    const int* row = edge_index;       // [E]
    const int* col = edge_index + E;   // [E]
    const int* rowh = row;             // first Eh: sorted user ids
    const int* colh = col;             // first Eh: item ids (random)

    // workspace layout:
    // urp[NU+1] | btotp[NBMAX*PAD] | bcurp[NBMAX*PAD] | bbase[NBMAX+1] | irp[NI+1] |
    // icols[Eh] | staging[Eh] | dinv[N] f |
    // yu01[NU*128] bf16 (128B-aligned) | y0i[NI*64] | yi12[NI*128] | y2u[NU*64]
    int*   urp     = (int*)d_ws;
    int*   btotp   = urp + (NU + 1);
    int*   bcurp   = btotp + NBMAX * PAD;
    int*   bbase   = bcurp + NBMAX * PAD;
    int*   irp     = bbase + (NBMAX + 1);
    int*   icols   = irp + (NI + 1);
    unsigned* staging = (unsigned*)(icols + Eh);
    float* dinv    = (float*)(staging + Eh);
    unsigned short* yu01 = (unsigned short*)(((uintptr_t)(dinv + N) + 127) & ~(uintptr_t)127);
    unsigned short* y0i  = yu01 + (long)NU * 128;
    unsigned short* yi12 = y0i + (long)NI * 64;
    unsigned short* y2u  = yi12 + (long)NI * 128;

    const int NB = (NI + BKT_SZ - 1) >> BKT_BITS;   // 98 for NI=100k (<= NBMAX)

    hipMemsetAsync(btotp, 0, (size_t)NBMAX * PAD * sizeof(int), stream);

    // K1: [users: urp + dinv + y0u] U [bucket counts]
    int UB = (NU + 15) / 16;
    int PC = (Eh + 4095) / 4096;
    k1_kernel<<<UB + PC, 256, 0, stream>>>(row, colh, urp, dinv, user_emb, yu01,
                                           btotp, NU, Eh, NB, UB);

    scanS_kernel<<<1, 256, 0, stream>>>(btotp, bbase, bcurp, NB, Eh);

    passA_kernel<<<(Eh + 1023) / 1024, 256, 0, stream>>>(rowh, colh, bcurp, staging,
                                                         Eh, NU, NB);

    passB_kernel<<<NB, 1024, 0, stream>>>(staging, bbase, irp, icols, dinv,
                                          item_emb, y0i, NU, NI, NB, Eh);

    // users L0: y1u (into yu01 y1-half)
    int nb_us = (int)(((long)NU * 16 + 255) / 256);
    ul0_kernel<<<nb_us, 256, 0, stream>>>(urp, col, dinv, y0i, yu01, NU);

    // D2: items L0+L1 (single paired gather on yu01) -> yi12
    int nb_it = (int)(((long)NI * 16 + 255) / 256);
    d2_kernel<<<nb_it, 256, 0, stream>>>(irp, icols, dinv, yu01, y0i, yi12, NU, NI);

    // D3: users L1+final (single paired gather on yi12) -> y2u, out[users]
    d3_kernel<<<nb_us, 256, 0, stream>>>(urp, col, dinv, yu01, yi12, y2u, out, NU);

    // D4: items final (gather y2u) -> out[items]
    d4_kernel<<<nb_it, 256, 0, stream>>>(irp, icols, dinv, y0i, yi12, y2u, out, NU, NI);
}